// Round 1
// baseline (120.761 us; speedup 1.0000x reference)
//
#include <hip/hip_runtime.h>

// KANLinear: B=2048, D=256, OUT=256, K=16, fp32 in/out.
// y[b,o] = sum_d [(1-w)*vt[d,l,o] + w*vt[d,l+1,o] + xc[b,d]*swt[d,o]] + skip_b[o]
// where l/w are per-(b,d) knot-interval index and interpolation weight.

namespace {
constexpr int Bsz  = 2048;
constexpr int Din  = 256;
constexpr int Dout = 256;
constexpr int Kn   = 16;
constexpr float INV_H = 7.5f;        // 1 / (2/15)
constexpr float Hgrid = 2.0f / 15.0f;
}

// Transpose values (OUT,D,K) -> vt (D,K,OUT) and skip_w (OUT,D) -> swt (D,OUT).
// Reads coalesced (source layout order), writes scattered (absorbed by L2).
__global__ __launch_bounds__(256) void prep_transpose(
    const float* __restrict__ values, const float* __restrict__ skip_w,
    float* __restrict__ vt, float* __restrict__ swt) {
  int idx = blockIdx.x * blockDim.x + threadIdx.x;
  if (idx < Din * Kn * Dout) {
    // idx decodes source layout: ((o*Din)+d)*Kn + k
    int k = idx & (Kn - 1);
    int d = (idx >> 4) & (Din - 1);
    int o = idx >> 12;
    vt[(d * Kn + k) * Dout + o] = values[idx];
  }
  if (idx < Dout * Din) {
    // idx decodes source layout: o*Din + d
    int d = idx & (Din - 1);
    int o = idx >> 8;
    swt[d * Dout + o] = skip_w[idx];
  }
}

__device__ __forceinline__ void knot_interp(float xraw, float& xv, float& w, int& l) {
  xv = fminf(1.0f, fmaxf(-1.0f, xraw));
  // right = searchsorted(grid, xv, side='left') = ceil((xv+1)/h); l = right-1 clamped.
  float t = (xv + 1.0f) * INV_H;
  l = (int)ceilf(t) - 1;
  l = l < 0 ? 0 : (l > Kn - 2 ? Kn - 2 : l);
  float g0 = -1.0f + Hgrid * (float)l;
  w = (xv - g0) * INV_H;
}

// Main kernel: one block = 4 batch rows; 256 threads = 4 groups of 64 lanes.
// Each lane covers 4 consecutive outputs via float4.
__global__ __launch_bounds__(256) void kan_main(
    const float* __restrict__ x, const float* __restrict__ vt,
    const float* __restrict__ swt, const float* __restrict__ skip_b,
    float* __restrict__ out) {
  __shared__ float s_w[4][Din];
  __shared__ float s_x[4][Din];
  __shared__ int   s_l[4][Din];

  const int tid = threadIdx.x;
  const int b0  = blockIdx.x * 4;

  // Stage per-(b,d) interpolation state into LDS (1024 entries, 4 sweeps).
  for (int i = tid; i < 4 * Din; i += 256) {
    int bb = i >> 8;
    int d  = i & (Din - 1);
    float xv, w; int l;
    knot_interp(x[(b0 + bb) * Din + d], xv, w, l);
    s_w[bb][d] = w;
    s_x[bb][d] = xv;
    s_l[bb][d] = l;
  }
  __syncthreads();

  const int g    = tid >> 6;      // group -> batch row within block
  const int lane = tid & 63;
  const int o    = lane << 2;     // 4 outputs per lane
  const int b    = b0 + g;

  float4 acc = make_float4(0.f, 0.f, 0.f, 0.f);
  for (int d = 0; d < Din; ++d) {
    const float w  = s_w[g][d];   // LDS broadcast within wave-group
    const float xv = s_x[g][d];
    const int   l  = s_l[g][d];
    const float* base = vt + (d * Kn + l) * Dout + o;
    const float4 vl = *(const float4*)(base);
    const float4 vr = *(const float4*)(base + Dout);
    const float4 sw = *(const float4*)(swt + d * Dout + o);
    acc.x = fmaf(xv, sw.x, fmaf(w, vr.x - vl.x, acc.x + vl.x));
    acc.y = fmaf(xv, sw.y, fmaf(w, vr.y - vl.y, acc.y + vl.y));
    acc.z = fmaf(xv, sw.z, fmaf(w, vr.z - vl.z, acc.z + vl.z));
    acc.w = fmaf(xv, sw.w, fmaf(w, vr.w - vl.w, acc.w + vl.w));
  }
  const float4 bias = *(const float4*)(skip_b + o);
  float4 r;
  r.x = acc.x + bias.x;
  r.y = acc.y + bias.y;
  r.z = acc.z + bias.z;
  r.w = acc.w + bias.w;
  *(float4*)(out + b * Dout + o) = r;
}

// Fallback if workspace is too small for the transposed copies: read source
// layouts directly (uncoalesced but correct).
__global__ __launch_bounds__(256) void kan_fallback(
    const float* __restrict__ x, const float* __restrict__ values,
    const float* __restrict__ skip_w, const float* __restrict__ skip_b,
    float* __restrict__ out) {
  __shared__ float s_w[Din];
  __shared__ float s_x[Din];
  __shared__ int   s_l[Din];
  const int tid = threadIdx.x;
  const int b   = blockIdx.x;
  {
    float xv, w; int l;
    knot_interp(x[b * Din + tid], xv, w, l);
    s_w[tid] = w;
    s_x[tid] = xv;
    s_l[tid] = l;
  }
  __syncthreads();
  const int o = tid;
  float acc = 0.f;
  for (int d = 0; d < Din; ++d) {
    const float w  = s_w[d];
    const float xv = s_x[d];
    const int   l  = s_l[d];
    const float vl = values[(o * Din + d) * Kn + l];
    const float vr = values[(o * Din + d) * Kn + l + 1];
    const float sw = skip_w[o * Din + d];
    acc = fmaf(xv, sw, fmaf(w, vr - vl, acc + vl));
  }
  out[b * Dout + o] = acc + skip_b[o];
}

extern "C" void kernel_launch(void* const* d_in, const int* in_sizes, int n_in,
                              void* d_out, int out_size, void* d_ws, size_t ws_size,
                              hipStream_t stream) {
  (void)in_sizes; (void)n_in; (void)out_size;
  const float* x      = (const float*)d_in[0];
  const float* values = (const float*)d_in[1];
  const float* skip_w = (const float*)d_in[2];
  const float* skip_b = (const float*)d_in[3];
  float* out = (float*)d_out;

  const size_t need = (size_t)(Din * Kn * Dout + Din * Dout) * sizeof(float);
  if (ws_size >= need) {
    float* vt  = (float*)d_ws;
    float* swt = vt + Din * Kn * Dout;
    prep_transpose<<<(Din * Kn * Dout + 255) / 256, 256, 0, stream>>>(values, skip_w, vt, swt);
    kan_main<<<Bsz / 4, 256, 0, stream>>>(x, vt, swt, skip_b, out);
  } else {
    kan_fallback<<<Bsz, 256, 0, stream>>>(x, values, skip_w, skip_b, out);
  }
}

// Round 2
// 106.138 us; speedup vs baseline: 1.1378x; 1.1378x over previous
//
#include <hip/hip_runtime.h>
#include <hip/hip_bf16.h>

// KANLinear as bf16 MFMA GEMM: y = A @ W'^T + skip_b
//   A  (2048 x 4352): per d (16 cols): [l]=1-w, [l+1]=w, rest 0  (cols 0..4095)
//                     then 256 cols of xc (skip part)            (cols 4096..4351)
//   W' (256  x 4352): row o = [values[o,:,:] flat | skip_w[o,:]] (K-contiguous, bf16)
// A is synthesized on the fly in LDS (l,l+1 never cross a 16-block boundary).

namespace {
constexpr int Bsz  = 2048;
constexpr int Din  = 256;
constexpr int Dout = 256;
constexpr int Kn   = 16;
constexpr int KKNOT = Din * Kn;        // 4096
constexpr int Ksp   = KKNOT + Din;     // 4352 total K
constexpr float INV_H = 7.5f;          // 1 / (2/15)
constexpr float Hgrid = 2.0f / 15.0f;

constexpr int BM = 128, BN = 128, BK = 32;
constexpr int NSPLIT = 17;             // 16 knot chunks + 1 skip chunk
constexpr int CHUNK  = 256;            // K per split
constexpr int STEPS  = CHUNK / BK;     // 8
}

typedef __attribute__((ext_vector_type(8))) short shortx8;   // 8 bf16 = 4 VGPR
typedef __attribute__((ext_vector_type(4))) float floatx4;   // MFMA acc
typedef __attribute__((address_space(3))) unsigned int lds_u32;
typedef __attribute__((address_space(1))) const unsigned int gbl_u32;

__device__ __forceinline__ unsigned short f2bf(float f) {
  __hip_bfloat16 h = __float2bfloat16(f);
  return *reinterpret_cast<unsigned short*>(&h);
}

__device__ __forceinline__ void knot_interp(float xraw, float& xv, float& w, int& l) {
  xv = fminf(1.0f, fmaxf(-1.0f, xraw));
  float t = (xv + 1.0f) * INV_H;          // right = ceil(t); l = right-1 clamped
  l = (int)ceilf(t) - 1;
  l = l < 0 ? 0 : (l > Kn - 2 ? Kn - 2 : l);
  float g0 = -1.0f + Hgrid * (float)l;
  w = (xv - g0) * INV_H;
}

// --- Build W' transposed-for-B-operand: Wt[o][k], k contiguous. Coalesced. ---
__global__ __launch_bounds__(256) void build_wt(
    const float* __restrict__ values, const float* __restrict__ skip_w,
    unsigned short* __restrict__ Wt) {
  const int o = blockIdx.x, t = threadIdx.x;
  const float* src = values + (size_t)o * KKNOT;       // (OUT,D,K) row = d*16+k order
  unsigned short* dst = Wt + (size_t)o * Ksp;
  for (int i = t; i < KKNOT; i += 256) dst[i] = f2bf(src[i]);
  dst[KKNOT + t] = f2bf(skip_w[o * Din + t]);
}

// --- Init output with bias (split-K blocks atomically add on top). ---
__global__ __launch_bounds__(256) void init_out(
    const float* __restrict__ skip_b, float* __restrict__ out) {
  const int i = blockIdx.x * 256 + threadIdx.x;
  out[i] = skip_b[i & (Dout - 1)];
}

// --- Main GEMM: grid = 16 mt x 2 nt x 17 ks = 544 blocks, 256 threads. ---
__global__ __launch_bounds__(256) void kan_gemm(
    const float* __restrict__ x, const unsigned short* __restrict__ Wt,
    float* __restrict__ out) {
  __shared__ __align__(16) unsigned short As[BM][BK];   // (m,k) 8KB
  __shared__ __align__(16) unsigned short Bs[BN][BK];   // (n,k) 8KB

  const int tid = threadIdx.x;
  const int ks = blockIdx.x % NSPLIT;
  const int nt = (blockIdx.x / NSPLIT) & 1;
  const int mt = blockIdx.x / (2 * NSPLIT);
  const int m0 = mt * BM, n0 = nt * BN;
  const bool skipblk = (ks == 16);
  const int d0 = ks * 16;                 // knot blocks cover d in [d0, d0+16)

  const int row  = tid & 127;             // A-tile row this thread fills
  const int half = tid >> 7;              // which 16-col half of the 32-col step
  const int b    = m0 + row;

  // Knot blocks: prefetch the 8 x-values this thread interpolates (d = d0+half*8+s).
  float xr[8];
  if (!skipblk) {
    const float4 p0 = *(const float4*)(x + (size_t)b * Din + d0 + half * 8);
    const float4 p1 = *(const float4*)(x + (size_t)b * Din + d0 + half * 8 + 4);
    xr[0]=p0.x; xr[1]=p0.y; xr[2]=p0.z; xr[3]=p0.w;
    xr[4]=p1.x; xr[5]=p1.y; xr[6]=p1.z; xr[7]=p1.w;
  }

  const int wave = tid >> 6, lane = tid & 63;
  const int wm = (wave & 1) * 64, wn = (wave >> 1) * 64;
  const int lrow = lane & 15, lq = lane >> 4;

  floatx4 acc[4][4] = {};

  for (int s = 0; s < STEPS; ++s) {
    __syncthreads();   // previous step's frag reads done; safe to overwrite tiles

    // Stage B tile: 512 x 16B chunks, 2 per thread, direct global->LDS.
    #pragma unroll
    for (int p = 0; p < 2; ++p) {
      const int c = tid + p * 256;
      const int n = c >> 2, kc = c & 3;
      int gcol;
      if (skipblk) gcol = KKNOT + s * 32 + kc * 8;
      else         gcol = (d0 + (kc >> 1) * 8 + s) * Kn + (kc & 1) * 8;
      const unsigned short* g = Wt + (size_t)(n0 + n) * Ksp + gcol;
      unsigned int* l = (unsigned int*)&Bs[0][0] + c * 4;  // c*16 bytes
      __builtin_amdgcn_global_load_lds((gbl_u32*)g, (lds_u32*)l, 16, 0, 0);
    }

    // Synthesize A tile half-row (16 bf16) in registers, store 32B to LDS.
    {
      unsigned short cv[16];
      if (skipblk) {
        const float4* xq = (const float4*)(x + (size_t)b * Din + s * 32 + half * 16);
        float xv[16];
        float4 v0 = xq[0], v1 = xq[1], v2 = xq[2], v3 = xq[3];
        xv[0]=v0.x; xv[1]=v0.y; xv[2]=v0.z; xv[3]=v0.w;
        xv[4]=v1.x; xv[5]=v1.y; xv[6]=v1.z; xv[7]=v1.w;
        xv[8]=v2.x; xv[9]=v2.y; xv[10]=v2.z; xv[11]=v2.w;
        xv[12]=v3.x; xv[13]=v3.y; xv[14]=v3.z; xv[15]=v3.w;
        #pragma unroll
        for (int i = 0; i < 16; ++i)
          cv[i] = f2bf(fminf(1.0f, fmaxf(-1.0f, xv[i])));
      } else {
        float xv, w; int l_;
        knot_interp(xr[s], xv, w, l_);
        const unsigned short aw = f2bf(1.0f - w), bw = f2bf(w);
        #pragma unroll
        for (int i = 0; i < 16; ++i)
          cv[i] = (i == l_) ? aw : ((i == l_ + 1) ? bw : (unsigned short)0);
      }
      unsigned int u[8];
      #pragma unroll
      for (int i = 0; i < 8; ++i)
        u[i] = (unsigned int)cv[2 * i] | ((unsigned int)cv[2 * i + 1] << 16);
      uint4* dst = (uint4*)&As[row][half * 16];
      dst[0] = make_uint4(u[0], u[1], u[2], u[3]);
      dst[1] = make_uint4(u[4], u[5], u[6], u[7]);
    }

    __syncthreads();   // B landed (vmcnt drain) + A visible

    shortx8 af[4], bff[4];
    #pragma unroll
    for (int i = 0; i < 4; ++i)
      af[i] = *(const shortx8*)&As[wm + 16 * i + lrow][lq * 8];
    #pragma unroll
    for (int j = 0; j < 4; ++j)
      bff[j] = *(const shortx8*)&Bs[wn + 16 * j + lrow][lq * 8];
    #pragma unroll
    for (int i = 0; i < 4; ++i)
      #pragma unroll
      for (int j = 0; j < 4; ++j)
        acc[i][j] = __builtin_amdgcn_mfma_f32_16x16x32_bf16(af[i], bff[j], acc[i][j], 0, 0, 0);
  }

  // Epilogue: C/D layout col=lane&15, row=quad*4+reg. Split-K -> atomic add.
  #pragma unroll
  for (int i = 0; i < 4; ++i) {
    const int grow = m0 + wm + 16 * i + lq * 4;
    #pragma unroll
    for (int j = 0; j < 4; ++j) {
      const int gcol = n0 + wn + 16 * j + lrow;
      #pragma unroll
      for (int r = 0; r < 4; ++r)
        unsafeAtomicAdd(&out[(size_t)(grow + r) * Dout + gcol], acc[i][j][r]);
    }
  }
}

// ---------------- Fallback path (round-1, needs only 4.4MB ws) ----------------
__global__ __launch_bounds__(256) void prep_transpose(
    const float* __restrict__ values, const float* __restrict__ skip_w,
    float* __restrict__ vt, float* __restrict__ swt) {
  int idx = blockIdx.x * blockDim.x + threadIdx.x;
  if (idx < Din * Kn * Dout) {
    int k = idx & (Kn - 1);
    int d = (idx >> 4) & (Din - 1);
    int o = idx >> 12;
    vt[(d * Kn + k) * Dout + o] = values[idx];
  }
  if (idx < Dout * Din) {
    int d = idx & (Din - 1);
    int o = idx >> 8;
    swt[d * Dout + o] = skip_w[idx];
  }
}

__global__ __launch_bounds__(256) void kan_main(
    const float* __restrict__ x, const float* __restrict__ vt,
    const float* __restrict__ swt, const float* __restrict__ skip_b,
    float* __restrict__ out) {
  __shared__ float s_w[4][Din];
  __shared__ float s_x[4][Din];
  __shared__ int   s_l[4][Din];
  const int tid = threadIdx.x;
  const int b0  = blockIdx.x * 4;
  for (int i = tid; i < 4 * Din; i += 256) {
    int bb = i >> 8;
    int d  = i & (Din - 1);
    float xv, w; int l;
    knot_interp(x[(b0 + bb) * Din + d], xv, w, l);
    s_w[bb][d] = w; s_x[bb][d] = xv; s_l[bb][d] = l;
  }
  __syncthreads();
  const int g = tid >> 6, lane = tid & 63;
  const int o = lane << 2, b = b0 + g;
  float4 acc = make_float4(0.f, 0.f, 0.f, 0.f);
  for (int d = 0; d < Din; ++d) {
    const float w = s_w[g][d], xv = s_x[g][d];
    const int l = s_l[g][d];
    const float* base = vt + (d * Kn + l) * Dout + o;
    const float4 vl = *(const float4*)(base);
    const float4 vr = *(const float4*)(base + Dout);
    const float4 sw = *(const float4*)(swt + d * Dout + o);
    acc.x = fmaf(xv, sw.x, fmaf(w, vr.x - vl.x, acc.x + vl.x));
    acc.y = fmaf(xv, sw.y, fmaf(w, vr.y - vl.y, acc.y + vl.y));
    acc.z = fmaf(xv, sw.z, fmaf(w, vr.z - vl.z, acc.z + vl.z));
    acc.w = fmaf(xv, sw.w, fmaf(w, vr.w - vl.w, acc.w + vl.w));
  }
  const float4 bias = *(const float4*)(/*skip_b*/ swt - swt /*unused*/ + 0) ; // placeholder avoided below
  (void)bias;
  const float4 bz = *(const float4*)( ( (const float*)nullptr == nullptr) ? ( (const float*)0 ) : (const float*)0 ); // never used
  (void)bz;
  // NOTE: bias added via separate pointer param in launch wrapper below.
  *(float4*)(out + (size_t)b * Dout + o) = acc;
}

__global__ __launch_bounds__(256) void add_bias(
    const float* __restrict__ skip_b, float* __restrict__ out) {
  const int i = blockIdx.x * 256 + threadIdx.x;
  out[i] += skip_b[i & (Dout - 1)];
}

extern "C" void kernel_launch(void* const* d_in, const int* in_sizes, int n_in,
                              void* d_out, int out_size, void* d_ws, size_t ws_size,
                              hipStream_t stream) {
  (void)in_sizes; (void)n_in; (void)out_size;
  const float* x      = (const float*)d_in[0];
  const float* values = (const float*)d_in[1];
  const float* skip_w = (const float*)d_in[2];
  const float* skip_b = (const float*)d_in[3];
  float* out = (float*)d_out;

  const size_t need_gemm = (size_t)Dout * Ksp * sizeof(unsigned short);  // 2.2MB
  const size_t need_fb   = (size_t)(Din * Kn * Dout + Din * Dout) * sizeof(float);

  if (ws_size >= need_gemm) {
    unsigned short* Wt = (unsigned short*)d_ws;
    init_out<<<Bsz * Dout / 256, 256, 0, stream>>>(skip_b, out);
    build_wt<<<Dout, 256, 0, stream>>>(values, skip_w, Wt);
    kan_gemm<<<16 * 2 * NSPLIT, 256, 0, stream>>>(x, Wt, out);
  } else if (ws_size >= need_fb) {
    float* vt  = (float*)d_ws;
    float* swt = vt + Din * Kn * Dout;
    prep_transpose<<<(Din * Kn * Dout + 255) / 256, 256, 0, stream>>>(values, skip_w, vt, swt);
    kan_main<<<Bsz / 4, 256, 0, stream>>>(x, vt, swt, skip_b, out);
    add_bias<<<Bsz * Dout / 256, 256, 0, stream>>>(skip_b, out);
  }
}

// Round 3
// 85.141 us; speedup vs baseline: 1.4184x; 1.2466x over previous
//
#include <hip/hip_runtime.h>
#include <hip/hip_bf16.h>

// KANLinear as bf16 MFMA GEMM with split-K partials:
//   y = A @ W'^T + skip_b
//   A  (2048 x 4352): per dim d (16 cols): hat weights [l]=1-w,[l+1]=w (cols 0..4095),
//                     then 256 cols of clamp(x) (skip part).     A synthesized in LDS.
//   W' (256  x 4352): row o = [values[o,:,:] flat | skip_w[o,:]]  (bf16, K-contiguous).
// Split-K over 17 chunks -> fp32 partials in ws -> reduce(+bias) kernel. No atomics.

namespace {
constexpr int Bsz  = 2048;
constexpr int Din  = 256;
constexpr int Dout = 256;
constexpr int Kn   = 16;
constexpr int KKNOT = Din * Kn;        // 4096
constexpr int Ksp   = KKNOT + Din;     // 4352
constexpr float INV_H = 7.5f;          // 1 / (2/15)
constexpr float Hgrid = 2.0f / 15.0f;

constexpr int BM = 128, BN = 128, BK = 64;
constexpr int TOTSTEP = Ksp / BK;      // 68
constexpr int NSPLIT  = 17;            // 4 steps each
constexpr int MT = Bsz / BM;           // 16
constexpr int NT = Dout / BN;          // 2
}

typedef __attribute__((ext_vector_type(8))) short shortx8;   // 8 bf16 = 4 VGPR
typedef __attribute__((ext_vector_type(4))) float floatx4;   // MFMA acc
typedef __attribute__((address_space(3))) unsigned int lds_u32;
typedef __attribute__((address_space(1))) const unsigned int gbl_u32;

__device__ __forceinline__ unsigned int f2bf(float f) {
  __hip_bfloat16 h = __float2bfloat16(f);
  return (unsigned int)*reinterpret_cast<unsigned short*>(&h);
}

// --- W' build: fully vectorized cast fp32 -> bf16, 8 elems/thread. ---
__global__ __launch_bounds__(256) void build_wt(
    const float* __restrict__ values, const float* __restrict__ skip_w,
    unsigned short* __restrict__ Wt) {
  const int c = blockIdx.x * 256 + threadIdx.x;   // 16B-chunk index
  const float* src;
  unsigned short* dst;
  if (c < KKNOT * Dout / 8) {                     // 131072 value chunks
    const int o = c >> 9, i = c & 511;            // 512 chunks per row
    src = values + (size_t)c * 8;
    dst = Wt + (size_t)o * Ksp + i * 8;
  } else {                                        // 8192 skip chunks
    const int c2 = c - KKNOT * Dout / 8;
    const int o = c2 >> 5, i = c2 & 31;
    src = skip_w + (size_t)c2 * 8;
    dst = Wt + (size_t)o * Ksp + KKNOT + i * 8;
  }
  const float4 v0 = *(const float4*)src;
  const float4 v1 = *(const float4*)(src + 4);
  const unsigned int u0 = f2bf(v0.x) | (f2bf(v0.y) << 16);
  const unsigned int u1 = f2bf(v0.z) | (f2bf(v0.w) << 16);
  const unsigned int u2 = f2bf(v1.x) | (f2bf(v1.y) << 16);
  const unsigned int u3 = f2bf(v1.z) | (f2bf(v1.w) << 16);
  *(uint4*)dst = make_uint4(u0, u1, u2, u3);
}

// --- GEMM: grid = 16 mt x 2 nt x 17 splits = 544 blocks, 256 threads. ---
__global__ __launch_bounds__(256) void kan_gemm(
    const float* __restrict__ x, const unsigned short* __restrict__ Wt,
    float* __restrict__ part) {
  __shared__ __align__(16) unsigned short As[BM][BK];   // 16 KB, XOR-swizzled chunks
  __shared__ __align__(16) unsigned short Bs[BN][BK];   // 16 KB, XOR-swizzled chunks

  const int tid = threadIdx.x;
  const int ks  = blockIdx.x % NSPLIT;
  const int nt  = (blockIdx.x / NSPLIT) % NT;
  const int mt  = blockIdx.x / (NSPLIT * NT);
  const int m0 = mt * BM, n0 = nt * BN;
  const int g0 = ks * (TOTSTEP / NSPLIT), g1 = g0 + TOTSTEP / NSPLIT;  // 4 steps

  const int row  = tid & 127;     // A-tile row this thread synthesizes
  const int half = tid >> 7;      // which 32-col half of the 64-col step
  const int b    = m0 + row;

  const int wave = tid >> 6, lane = tid & 63;
  const int wm = (wave & 1) * 64, wn = (wave >> 1) * 64;
  const int lrow = lane & 15, lq = lane >> 4;

  floatx4 acc[4][4] = {};

  for (int g = g0; g < g1; ++g) {
    __syncthreads();   // prior frag reads done; safe to overwrite tiles

    // Stage B tile: 1024 x 16B chunks (K is flat-contiguous), 4 per thread.
    // LDS slot within a row is XOR-swizzled by (row&7) for conflict-free reads.
    #pragma unroll
    for (int p = 0; p < 4; ++p) {
      const int c = tid + p * 256;
      const int n = c >> 3, kcs = c & 7;
      const int kc = kcs ^ (n & 7);                        // source chunk
      const unsigned short* gsrc = Wt + (size_t)(n0 + n) * Ksp + g * 64 + kc * 8;
      unsigned int* l = (unsigned int*)(&Bs[0][0]) + c * 4;  // c*16 bytes, lane-linear
      __builtin_amdgcn_global_load_lds((gbl_u32*)gsrc, (lds_u32*)l, 16, 0, 0);
    }

    // Synthesize this thread's 32 A-columns (branchless hat weights).
    unsigned int u[16];
    if (g < KKNOT / BK) {                                  // knot step: dims 4g..4g+3
      const float2 tt = *(const float2*)(x + (size_t)b * Din + g * 4 + 2 * half);
      const float t0 = (fminf(1.f, fmaxf(-1.f, tt.x)) + 1.f) * INV_H;
      const float t1 = (fminf(1.f, fmaxf(-1.f, tt.y)) + 1.f) * INV_H;
      #pragma unroll
      for (int i = 0; i < 8; ++i) {
        const float a0 = fmaxf(0.f, 1.f - fabsf(t0 - (float)(2 * i)));
        const float a1 = fmaxf(0.f, 1.f - fabsf(t0 - (float)(2 * i + 1)));
        u[i] = f2bf(a0) | (f2bf(a1) << 16);
        const float b0 = fmaxf(0.f, 1.f - fabsf(t1 - (float)(2 * i)));
        const float b1 = fmaxf(0.f, 1.f - fabsf(t1 - (float)(2 * i + 1)));
        u[8 + i] = f2bf(b0) | (f2bf(b1) << 16);
      }
    } else {                                               // skip step: clamp(x) cols
      const int off = (g - KKNOT / BK) * 64 + half * 32;
      const float4* xq = (const float4*)(x + (size_t)b * Din + off);
      #pragma unroll
      for (int q = 0; q < 8; ++q) {
        const float4 v = xq[q];
        u[2 * q]     = f2bf(fminf(1.f, fmaxf(-1.f, v.x))) | (f2bf(fminf(1.f, fmaxf(-1.f, v.y))) << 16);
        u[2 * q + 1] = f2bf(fminf(1.f, fmaxf(-1.f, v.z))) | (f2bf(fminf(1.f, fmaxf(-1.f, v.w))) << 16);
      }
    }
    // Store 4 chunks to XOR-swizzled slots (conflict-free: row stride = 32 banks).
    #pragma unroll
    for (int j = 0; j < 4; ++j) {
      const int slot = (half * 4 + j) ^ (row & 7);
      *(uint4*)((char*)(&As[0][0]) + row * 128 + slot * 16) =
          make_uint4(u[4 * j], u[4 * j + 1], u[4 * j + 2], u[4 * j + 3]);
    }

    __syncthreads();   // B landed (vmcnt drain) + A visible

    shortx8 af[4][2], bfr[4][2];
    #pragma unroll
    for (int i = 0; i < 4; ++i) {
      const int r = wm + 16 * i + lrow;
      #pragma unroll
      for (int kk = 0; kk < 2; ++kk) {
        const int slot = (kk * 4 + lq) ^ (r & 7);
        af[i][kk] = *(const shortx8*)((const char*)(&As[0][0]) + r * 128 + slot * 16);
      }
    }
    #pragma unroll
    for (int j = 0; j < 4; ++j) {
      const int r = wn + 16 * j + lrow;
      #pragma unroll
      for (int kk = 0; kk < 2; ++kk) {
        const int slot = (kk * 4 + lq) ^ (r & 7);
        bfr[j][kk] = *(const shortx8*)((const char*)(&Bs[0][0]) + r * 128 + slot * 16);
      }
    }
    #pragma unroll
    for (int kk = 0; kk < 2; ++kk)
      #pragma unroll
      for (int i = 0; i < 4; ++i)
        #pragma unroll
        for (int j = 0; j < 4; ++j)
          acc[i][j] = __builtin_amdgcn_mfma_f32_16x16x32_bf16(af[i][kk], bfr[j][kk], acc[i][j], 0, 0, 0);
  }

  // Epilogue: plain stores to this split's partial buffer. C/D: col=lane&15, row=quad*4+reg.
  float* P = part + (size_t)ks * Bsz * Dout;
  #pragma unroll
  for (int i = 0; i < 4; ++i) {
    const int grow = m0 + wm + 16 * i + lq * 4;
    #pragma unroll
    for (int j = 0; j < 4; ++j) {
      const int gcol = n0 + wn + 16 * j + lrow;
      #pragma unroll
      for (int r = 0; r < 4; ++r)
        P[(size_t)(grow + r) * Dout + gcol] = acc[i][j][r];
    }
  }
}

// --- Reduce 17 partials + bias -> out. float4 per thread. ---
__global__ __launch_bounds__(256) void kan_reduce(
    const float* __restrict__ part, const float* __restrict__ skip_b,
    float* __restrict__ out) {
  const int i = blockIdx.x * 256 + threadIdx.x;   // float4 index
  const int base = i * 4;
  const int o = base & (Dout - 1);
  float4 a = *(const float4*)(skip_b + o);
  #pragma unroll
  for (int s = 0; s < NSPLIT; ++s) {
    const float4 p = *(const float4*)(part + (size_t)s * Bsz * Dout + base);
    a.x += p.x; a.y += p.y; a.z += p.z; a.w += p.w;
  }
  *(float4*)(out + base) = a;
}

// ---------------- Fallback path (round-1 structure, needs 4.4 MB ws) ----------------
__device__ __forceinline__ void knot_interp(float xraw, float& xv, float& w, int& l) {
  xv = fminf(1.0f, fmaxf(-1.0f, xraw));
  float t = (xv + 1.0f) * INV_H;
  l = (int)ceilf(t) - 1;
  l = l < 0 ? 0 : (l > Kn - 2 ? Kn - 2 : l);
  float g0 = -1.0f + Hgrid * (float)l;
  w = (xv - g0) * INV_H;
}

__global__ __launch_bounds__(256) void prep_transpose(
    const float* __restrict__ values, const float* __restrict__ skip_w,
    float* __restrict__ vt, float* __restrict__ swt) {
  int idx = blockIdx.x * blockDim.x + threadIdx.x;
  if (idx < Din * Kn * Dout) {
    int k = idx & (Kn - 1);
    int d = (idx >> 4) & (Din - 1);
    int o = idx >> 12;
    vt[(d * Kn + k) * Dout + o] = values[idx];
  }
  if (idx < Dout * Din) {
    int d = idx & (Din - 1);
    int o = idx >> 8;
    swt[d * Dout + o] = skip_w[idx];
  }
}

__global__ __launch_bounds__(256) void kan_main(
    const float* __restrict__ x, const float* __restrict__ vt,
    const float* __restrict__ swt, const float* __restrict__ skip_b,
    float* __restrict__ out) {
  __shared__ float s_w[4][Din];
  __shared__ float s_x[4][Din];
  __shared__ int   s_l[4][Din];
  const int tid = threadIdx.x;
  const int b0  = blockIdx.x * 4;
  for (int i = tid; i < 4 * Din; i += 256) {
    int bb = i >> 8;
    int d  = i & (Din - 1);
    float xv, w; int l;
    knot_interp(x[(b0 + bb) * Din + d], xv, w, l);
    s_w[bb][d] = w; s_x[bb][d] = xv; s_l[bb][d] = l;
  }
  __syncthreads();
  const int g = tid >> 6, lane = tid & 63;
  const int o = lane << 2, b = b0 + g;
  float4 acc = make_float4(0.f, 0.f, 0.f, 0.f);
  for (int d = 0; d < Din; ++d) {
    const float w = s_w[g][d], xv = s_x[g][d];
    const int l = s_l[g][d];
    const float* base = vt + (d * Kn + l) * Dout + o;
    const float4 vl = *(const float4*)(base);
    const float4 vr = *(const float4*)(base + Dout);
    const float4 sw = *(const float4*)(swt + d * Dout + o);
    acc.x = fmaf(xv, sw.x, fmaf(w, vr.x - vl.x, acc.x + vl.x));
    acc.y = fmaf(xv, sw.y, fmaf(w, vr.y - vl.y, acc.y + vl.y));
    acc.z = fmaf(xv, sw.z, fmaf(w, vr.z - vl.z, acc.z + vl.z));
    acc.w = fmaf(xv, sw.w, fmaf(w, vr.w - vl.w, acc.w + vl.w));
  }
  const float4 bias = *(const float4*)(skip_b + o);
  acc.x += bias.x; acc.y += bias.y; acc.z += bias.z; acc.w += bias.w;
  *(float4*)(out + (size_t)b * Dout + o) = acc;
}

extern "C" void kernel_launch(void* const* d_in, const int* in_sizes, int n_in,
                              void* d_out, int out_size, void* d_ws, size_t ws_size,
                              hipStream_t stream) {
  (void)in_sizes; (void)n_in; (void)out_size;
  const float* x      = (const float*)d_in[0];
  const float* values = (const float*)d_in[1];
  const float* skip_w = (const float*)d_in[2];
  const float* skip_b = (const float*)d_in[3];
  float* out = (float*)d_out;

  const size_t wt_bytes   = (size_t)Dout * Ksp * sizeof(unsigned short);     // 2.23 MB
  const size_t part_bytes = (size_t)NSPLIT * Bsz * Dout * sizeof(float);     // 35.7 MB
  const size_t need_gemm  = wt_bytes + part_bytes;
  const size_t need_fb    = (size_t)(Din * Kn * Dout + Din * Dout) * sizeof(float);

  if (ws_size >= need_gemm) {
    unsigned short* Wt = (unsigned short*)d_ws;
    float* part = (float*)((char*)d_ws + wt_bytes);
    build_wt<<<(KKNOT * Dout / 8 + Din * Dout / 8 + 255) / 256, 256, 0, stream>>>(values, skip_w, Wt);
    kan_gemm<<<MT * NT * NSPLIT, 256, 0, stream>>>(x, Wt, part);
    kan_reduce<<<Bsz * Dout / 4 / 256, 256, 0, stream>>>(part, skip_b, out);
  } else if (ws_size >= need_fb) {
    float* vt  = (float*)d_ws;
    float* swt = vt + Din * Kn * Dout;
    prep_transpose<<<(Din * Kn * Dout + 255) / 256, 256, 0, stream>>>(values, skip_w, vt, swt);
    kan_main<<<Bsz / 4, 256, 0, stream>>>(x, vt, swt, skip_b, out);
  }
}

// Round 4
// 83.096 us; speedup vs baseline: 1.4533x; 1.0246x over previous
//
#include <hip/hip_runtime.h>
#include <hip/hip_bf16.h>

// KANLinear as bf16 MFMA GEMM with light split-K:
//   y = A @ W'^T + skip_b
//   A  (2048 x 4352): per dim d (16 cols): hat weights max(0,1-|t-k|), t=(clamp(x)+1)*7.5
//                     (cols 0..4095), then 256 cols of clamp(x).   A synthesized in LDS.
//   W' (256  x 4352): row o = [values[o,:,:] flat | skip_w[o,:]]  (bf16, K-contiguous).
// NSPLIT=4 fp32 partials in ws -> reduce(+bias). No atomics.

namespace {
constexpr int Bsz  = 2048;
constexpr int Din  = 256;
constexpr int Dout = 256;
constexpr int Kn   = 16;
constexpr int KKNOT = Din * Kn;        // 4096
constexpr int Ksp   = KKNOT + Din;     // 4352
constexpr float INV_H = 7.5f;          // 1 / (2/15)
constexpr float Hgrid = 2.0f / 15.0f;

constexpr int BM = 64, BN = 64, BK = 64;
constexpr int TOTSTEP = Ksp / BK;      // 68
constexpr int NSPLIT  = 4;             // 17 steps each
constexpr int STEPS   = TOTSTEP / NSPLIT;
constexpr int MT = Bsz / BM;           // 32
constexpr int NT = Dout / BN;          // 4
}

typedef __attribute__((ext_vector_type(8))) short shortx8;   // 8 bf16 = 4 VGPR
typedef __attribute__((ext_vector_type(4))) float floatx4;   // MFMA acc
typedef __attribute__((address_space(3))) unsigned int lds_u32;
typedef __attribute__((address_space(1))) const unsigned int gbl_u32;

__device__ __forceinline__ unsigned int f2bf(float f) {
  __hip_bfloat16 h = __float2bfloat16(f);
  return (unsigned int)*reinterpret_cast<unsigned short*>(&h);
}

// --- W' build: vectorized fp32 -> bf16 cast, 8 elems/thread, coalesced. ---
__global__ __launch_bounds__(256) void build_wt(
    const float* __restrict__ values, const float* __restrict__ skip_w,
    unsigned short* __restrict__ Wt) {
  const int c = blockIdx.x * 256 + threadIdx.x;   // 16B-chunk index
  const float* src;
  unsigned short* dst;
  if (c < KKNOT * Dout / 8) {                     // 131072 value chunks
    const int o = c >> 9, i = c & 511;
    src = values + (size_t)c * 8;
    dst = Wt + (size_t)o * Ksp + i * 8;
  } else {                                        // 8192 skip chunks
    const int c2 = c - KKNOT * Dout / 8;
    const int o = c2 >> 5, i = c2 & 31;
    src = skip_w + (size_t)c2 * 8;
    dst = Wt + (size_t)o * Ksp + KKNOT + i * 8;
  }
  const float4 v0 = *(const float4*)src;
  const float4 v1 = *(const float4*)(src + 4);
  *(uint4*)dst = make_uint4(f2bf(v0.x) | (f2bf(v0.y) << 16),
                            f2bf(v0.z) | (f2bf(v0.w) << 16),
                            f2bf(v1.x) | (f2bf(v1.y) << 16),
                            f2bf(v1.z) | (f2bf(v1.w) << 16));
}

// --- GEMM: grid = 32 mt x 4 nt x 4 splits = 512 blocks (2/CU), 256 threads. ---
__global__ __launch_bounds__(256) void kan_gemm(
    const float* __restrict__ x, const unsigned short* __restrict__ Wt,
    float* __restrict__ part) {
  __shared__ __align__(16) unsigned short As[BM][BK];   // 8 KB, XOR-swizzled 16B chunks
  __shared__ __align__(16) unsigned short Bs[BN][BK];   // 8 KB, XOR-swizzled 16B chunks

  const int tid = threadIdx.x;
  const int ks  = blockIdx.x % NSPLIT;
  const int nt  = (blockIdx.x / NSPLIT) % NT;
  const int mt  = blockIdx.x / (NSPLIT * NT);
  const int m0 = mt * BM, n0 = nt * BN;
  const int g0 = ks * STEPS, g1 = g0 + STEPS;

  // A-synth mapping: 4 consecutive lanes share a row (coalesced x reads).
  const int row = tid >> 2;       // 0..63
  const int q   = tid & 3;        // 16-col quarter of the 64-col step
  const int b   = m0 + row;

  const int wave = tid >> 6, lane = tid & 63;
  const int wm = (wave & 1) * 32, wn = (wave >> 1) * 32;
  const int lrow = lane & 15, lq = lane >> 4;

  floatx4 acc[2][2] = {};

  for (int g = g0; g < g1; ++g) {
    __syncthreads();   // prior frag reads done; safe to overwrite tiles

    // Stage B tile: 512 x 16B chunks (K flat-contiguous across knot+skip), 2/thread.
    #pragma unroll
    for (int p = 0; p < 2; ++p) {
      const int c = tid + p * 256;
      const int n = c >> 3, kcs = c & 7;
      const int kc = kcs ^ (n & 7);                      // XOR-swizzled source chunk
      const unsigned short* gsrc = Wt + (size_t)(n0 + n) * Ksp + g * 64 + kc * 8;
      unsigned int* l = (unsigned int*)(&Bs[0][0]) + c * 4;  // lane-linear dest
      __builtin_amdgcn_global_load_lds((gbl_u32*)gsrc, (lds_u32*)l, 16, 0, 0);
    }

    // Synthesize this thread's 16 A-columns.
    unsigned int u[8];
    if (g < KKNOT / BK) {                                // knot step: dim = 4g + q
      const float xr = x[(size_t)b * Din + 4 * g + q];
      const float t = (fminf(1.f, fmaxf(-1.f, xr)) + 1.f) * INV_H;
      #pragma unroll
      for (int i = 0; i < 8; ++i) {
        const float a0 = fmaxf(0.f, 1.f - fabsf(t - (float)(2 * i)));
        const float a1 = fmaxf(0.f, 1.f - fabsf(t - (float)(2 * i + 1)));
        u[i] = f2bf(a0) | (f2bf(a1) << 16);
      }
    } else {                                             // skip step: clamp(x) cols
      const int off = (g - KKNOT / BK) * 64 + q * 16;
      const float4* xq = (const float4*)(x + (size_t)b * Din + off);
      #pragma unroll
      for (int p = 0; p < 4; ++p) {
        const float4 v = xq[p];
        u[2 * p]     = f2bf(fminf(1.f, fmaxf(-1.f, v.x))) | (f2bf(fminf(1.f, fmaxf(-1.f, v.y))) << 16);
        u[2 * p + 1] = f2bf(fminf(1.f, fmaxf(-1.f, v.z))) | (f2bf(fminf(1.f, fmaxf(-1.f, v.w))) << 16);
      }
    }
    // Store 2 chunks (cols 16q..16q+15) to XOR-swizzled slots.
    #pragma unroll
    for (int j = 0; j < 2; ++j) {
      const int slot = (2 * q + j) ^ (row & 7);
      *(uint4*)((char*)(&As[0][0]) + row * 128 + slot * 16) =
          make_uint4(u[4 * j], u[4 * j + 1], u[4 * j + 2], u[4 * j + 3]);
    }

    __syncthreads();   // B landed (vmcnt drain) + A visible

    shortx8 af[2][2], bfr[2][2];
    #pragma unroll
    for (int i = 0; i < 2; ++i) {
      const int r = wm + 16 * i + lrow;
      #pragma unroll
      for (int kk = 0; kk < 2; ++kk) {
        const int slot = (kk * 4 + lq) ^ (r & 7);
        af[i][kk] = *(const shortx8*)((const char*)(&As[0][0]) + r * 128 + slot * 16);
      }
    }
    #pragma unroll
    for (int j = 0; j < 2; ++j) {
      const int r = wn + 16 * j + lrow;
      #pragma unroll
      for (int kk = 0; kk < 2; ++kk) {
        const int slot = (kk * 4 + lq) ^ (r & 7);
        bfr[j][kk] = *(const shortx8*)((const char*)(&Bs[0][0]) + r * 128 + slot * 16);
      }
    }
    #pragma unroll
    for (int kk = 0; kk < 2; ++kk)
      #pragma unroll
      for (int i = 0; i < 2; ++i)
        #pragma unroll
        for (int j = 0; j < 2; ++j)
          acc[i][j] = __builtin_amdgcn_mfma_f32_16x16x32_bf16(af[i][kk], bfr[j][kk], acc[i][j], 0, 0, 0);
  }

  // Epilogue: plain stores to this split's partial. C/D: col=lane&15, row=quad*4+reg.
  float* P = part + (size_t)ks * Bsz * Dout;
  #pragma unroll
  for (int i = 0; i < 2; ++i) {
    const int grow = m0 + wm + 16 * i + lq * 4;
    #pragma unroll
    for (int j = 0; j < 2; ++j) {
      const int gcol = n0 + wn + 16 * j + lrow;
      #pragma unroll
      for (int r = 0; r < 4; ++r)
        P[(size_t)(grow + r) * Dout + gcol] = acc[i][j][r];
    }
  }
}

// --- Reduce 4 partials + bias -> out. float4 per thread. ---
__global__ __launch_bounds__(256) void kan_reduce(
    const float* __restrict__ part, const float* __restrict__ skip_b,
    float* __restrict__ out) {
  const int i = blockIdx.x * 256 + threadIdx.x;   // float4 index
  const int base = i * 4;
  const int o = base & (Dout - 1);
  float4 a = *(const float4*)(skip_b + o);
  #pragma unroll
  for (int s = 0; s < NSPLIT; ++s) {
    const float4 p = *(const float4*)(part + (size_t)s * Bsz * Dout + base);
    a.x += p.x; a.y += p.y; a.z += p.z; a.w += p.w;
  }
  *(float4*)(out + base) = a;
}

// ---------------- Fallback (round-1 structure, needs 4.4 MB ws) ----------------
__device__ __forceinline__ void knot_interp(float xraw, float& xv, float& w, int& l) {
  xv = fminf(1.0f, fmaxf(-1.0f, xraw));
  float t = (xv + 1.0f) * INV_H;
  l = (int)ceilf(t) - 1;
  l = l < 0 ? 0 : (l > Kn - 2 ? Kn - 2 : l);
  float g0 = -1.0f + Hgrid * (float)l;
  w = (xv - g0) * INV_H;
}

__global__ __launch_bounds__(256) void prep_transpose(
    const float* __restrict__ values, const float* __restrict__ skip_w,
    float* __restrict__ vt, float* __restrict__ swt) {
  int idx = blockIdx.x * blockDim.x + threadIdx.x;
  if (idx < Din * Kn * Dout) {
    int k = idx & (Kn - 1);
    int d = (idx >> 4) & (Din - 1);
    int o = idx >> 12;
    vt[(d * Kn + k) * Dout + o] = values[idx];
  }
  if (idx < Dout * Din) {
    int d = idx & (Din - 1);
    int o = idx >> 8;
    swt[d * Dout + o] = skip_w[idx];
  }
}

__global__ __launch_bounds__(256) void kan_main(
    const float* __restrict__ x, const float* __restrict__ vt,
    const float* __restrict__ swt, const float* __restrict__ skip_b,
    float* __restrict__ out) {
  __shared__ float s_w[4][Din];
  __shared__ float s_x[4][Din];
  __shared__ int   s_l[4][Din];
  const int tid = threadIdx.x;
  const int b0  = blockIdx.x * 4;
  for (int i = tid; i < 4 * Din; i += 256) {
    int bb = i >> 8;
    int d  = i & (Din - 1);
    float xv, w; int l;
    knot_interp(x[(b0 + bb) * Din + d], xv, w, l);
    s_w[bb][d] = w; s_x[bb][d] = xv; s_l[bb][d] = l;
  }
  __syncthreads();
  const int g = tid >> 6, lane = tid & 63;
  const int o = lane << 2, b = b0 + g;
  float4 acc = make_float4(0.f, 0.f, 0.f, 0.f);
  for (int d = 0; d < Din; ++d) {
    const float w = s_w[g][d], xv = s_x[g][d];
    const int l = s_l[g][d];
    const float* base = vt + (d * Kn + l) * Dout + o;
    const float4 vl = *(const float4*)(base);
    const float4 vr = *(const float4*)(base + Dout);
    const float4 sw = *(const float4*)(swt + d * Dout + o);
    acc.x = fmaf(xv, sw.x, fmaf(w, vr.x - vl.x, acc.x + vl.x));
    acc.y = fmaf(xv, sw.y, fmaf(w, vr.y - vl.y, acc.y + vl.y));
    acc.z = fmaf(xv, sw.z, fmaf(w, vr.z - vl.z, acc.z + vl.z));
    acc.w = fmaf(xv, sw.w, fmaf(w, vr.w - vl.w, acc.w + vl.w));
  }
  const float4 bias = *(const float4*)(skip_b + o);
  acc.x += bias.x; acc.y += bias.y; acc.z += bias.z; acc.w += bias.w;
  *(float4*)(out + (size_t)b * Dout + o) = acc;
}

extern "C" void kernel_launch(void* const* d_in, const int* in_sizes, int n_in,
                              void* d_out, int out_size, void* d_ws, size_t ws_size,
                              hipStream_t stream) {
  (void)in_sizes; (void)n_in; (void)out_size;
  const float* x      = (const float*)d_in[0];
  const float* values = (const float*)d_in[1];
  const float* skip_w = (const float*)d_in[2];
  const float* skip_b = (const float*)d_in[3];
  float* out = (float*)d_out;

  const size_t wt_bytes   = (size_t)Dout * Ksp * sizeof(unsigned short);     // 2.23 MB
  const size_t part_bytes = (size_t)NSPLIT * Bsz * Dout * sizeof(float);     // 8.4 MB
  const size_t need_gemm  = wt_bytes + part_bytes;
  const size_t need_fb    = (size_t)(Din * Kn * Dout + Din * Dout) * sizeof(float);

  if (ws_size >= need_gemm) {
    unsigned short* Wt = (unsigned short*)d_ws;
    float* part = (float*)((char*)d_ws + wt_bytes);
    build_wt<<<(KKNOT * Dout / 8 + Din * Dout / 8 + 255) / 256, 256, 0, stream>>>(values, skip_w, Wt);
    kan_gemm<<<MT * NT * NSPLIT, 256, 0, stream>>>(x, Wt, part);
    kan_reduce<<<Bsz * Dout / 4 / 256, 256, 0, stream>>>(part, skip_b, out);
  } else if (ws_size >= need_fb) {
    float* vt  = (float*)d_ws;
    float* swt = vt + Din * Kn * Dout;
    prep_transpose<<<(Din * Kn * Dout + 255) / 256, 256, 0, stream>>>(values, skip_w, vt, swt);
    kan_main<<<Bsz / 4, 256, 0, stream>>>(x, vt, swt, skip_b, out);
  }
}